// Round 7
// baseline (86.879 us; speedup 1.0000x reference)
//
#include <hip/hip_runtime.h>
#include <stdint.h>

#define B_SIZE        262144
#define NUM_CLASSES   1000
#define CODE_LEN      512
#define PACKED_WORDS  (NUM_CLASSES * 16)        // 16000 uint32 = 62.5 KB
#define CHUNKS        (NUM_CLASSES * 4)         // 4000 uint4 chunks
#define NBLOCKS       256
#define SAMPLES_PER_BLOCK (B_SIZE / NBLOCKS)    // 1024 -> 4 per thread
#define PACKERS       250                       // blocks 0..249 pack 64 words each

// ws layout (bytes):
//   [0]      u32 partials[NBLOCKS], one per 128B line (stride 32 u32)
//   [32768]  u32 flags[PACKERS],   one per 128B line (stride 32 u32)
//   [65536]  packed codebook, 16000 u32 (written by device-scope atomics)
#define WS_PART_OFF     0
#define WS_FLAG_OFF     32768
#define WS_PACKED_OFF   65536
#define WS_LINE_STRIDE  32            // u32 elements = 128 B
#define PUB_MARKER      0x40000000u   // bit30: poison 0xAAAAAAAA has bit30=0
#define FLAG_MARKER     0x13572468u   // != 0xAAAAAAAA poison

// Single fused kernel:
//  Phase 1: blocks 0..249 ballot-pack their 2048-float slice of the codebook
//           and publish 64 packed words via device-scope atomicExch (-> LLC),
//           then release their own flag line.
//  Phase 2: all blocks spin on the 250 flag lines with pure acquire loads
//           (one thread per line; contention-free, no RMW).
//  Phase 3: stage packed table -> LDS with bank swizzle.
//  Phase 4: 4 samples/thread XOR+popcount gathers, wave+block reduce.
//  Phase 5: publish block partial to its own line; block 0 collects and
//           writes the mean.
__global__ __launch_bounds__(256) void hamming_fused_kernel(
        const int* __restrict__ output,
        const int* __restrict__ target,
        const float* __restrict__ codebook,
        unsigned int* __restrict__ partials,
        unsigned int* __restrict__ flags,
        unsigned int* __restrict__ packed) {
    __shared__ uint4 lds[CHUNKS];               // 64000 B
    __shared__ unsigned int wsum[4];

    // Prefetch this thread's 8 indices: loads issue now, complete during
    // pack/spin/staging.
    int base = blockIdx.x * SAMPLES_PER_BLOCK + threadIdx.x;
    int o[4], t[4];
    #pragma unroll
    for (int b = 0; b < 4; b++) {
        o[b] = output[base + b * 256];
        t[b] = target[base + b * 256];
    }

    // ---- Phase 1: distributed pack (blocks 0..249) ----
    if (blockIdx.x < PACKERS) {
        int base_e = blockIdx.x * 2048;
        #pragma unroll
        for (int i = 0; i < 8; i++) {
            int idx = base_e + i * 256 + threadIdx.x;
            float x = codebook[idx];
            unsigned long long m = __ballot(x > 0.5f);
            if ((threadIdx.x & 31) == 0) {
                // device-scope atomic store -> performed at LLC
                atomicExch(&packed[idx >> 5],
                           (unsigned int)(m >> (threadIdx.x & 32)));
            }
        }
        __syncthreads();          // all waves' exchs drained (vmcnt before barrier)
        if (threadIdx.x == 0) {
            __threadfence();      // order flag after the word atomics
            atomicExch(&flags[blockIdx.x * WS_LINE_STRIDE], FLAG_MARKER);
        }
    }

    // ---- Phase 2: flag barrier (contention-free: one thread per line) ----
    if (threadIdx.x < PACKERS) {
        while (__hip_atomic_load(&flags[threadIdx.x * WS_LINE_STRIDE],
                                 __ATOMIC_ACQUIRE,
                                 __HIP_MEMORY_SCOPE_AGENT) != FLAG_MARKER) {}
    }
    __syncthreads();

    // ---- Phase 3: stage packed table -> LDS with bank swizzle ----
    // chunk k of row r stored at lds[4r + ((k + (r>>2)) & 3)]
    const uint4* pk4 = (const uint4*)packed;
    #pragma unroll
    for (int it = 0; it < 16; it++) {
        int g = threadIdx.x + 256 * it;
        if (g < CHUNKS) {
            int r = g >> 2, k = g & 3;
            lds[(r << 2) + ((k + (r >> 2)) & 3)] = pk4[g];
        }
    }
    __syncthreads();

    // ---- Phase 4: gathers + popcount ----
    unsigned int sum = 0;
    #pragma unroll
    for (int b = 0; b < 2; b++) {
        int o0 = o[2 * b], t0 = t[2 * b];
        int o1 = o[2 * b + 1], t1 = t[2 * b + 1];

        uint4 ao[4], at[4], bo[4], bt[4];
        int so0 = (o0 >> 2) & 3, st0 = (t0 >> 2) & 3;
        int so1 = (o1 >> 2) & 3, st1 = (t1 >> 2) & 3;
        #pragma unroll
        for (int k = 0; k < 4; k++) ao[k] = lds[(o0 << 2) + ((k + so0) & 3)];
        #pragma unroll
        for (int k = 0; k < 4; k++) at[k] = lds[(t0 << 2) + ((k + st0) & 3)];
        #pragma unroll
        for (int k = 0; k < 4; k++) bo[k] = lds[(o1 << 2) + ((k + so1) & 3)];
        #pragma unroll
        for (int k = 0; k < 4; k++) bt[k] = lds[(t1 << 2) + ((k + st1) & 3)];

        #pragma unroll
        for (int k = 0; k < 4; k++) {
            sum += __popc(ao[k].x ^ at[k].x) + __popc(ao[k].y ^ at[k].y)
                 + __popc(ao[k].z ^ at[k].z) + __popc(ao[k].w ^ at[k].w);
            sum += __popc(bo[k].x ^ bt[k].x) + __popc(bo[k].y ^ bt[k].y)
                 + __popc(bo[k].z ^ bt[k].z) + __popc(bo[k].w ^ bt[k].w);
        }
    }

    // wave(64)-level reduction, then block reduction in LDS
    #pragma unroll
    for (int off = 32; off > 0; off >>= 1)
        sum += __shfl_down(sum, off, 64);
    if ((threadIdx.x & 63) == 0)
        wsum[threadIdx.x >> 6] = sum;
    __syncthreads();

    // ---- Phase 5: publish + block-0 finalize ----
    if (threadIdx.x == 0) {
        unsigned int bsum = wsum[0] + wsum[1] + wsum[2] + wsum[3];
        atomicExch(&partials[blockIdx.x * WS_LINE_STRIDE], bsum | PUB_MARKER);
    }
}

// block 0 finalize lives in the same kernel via a second entry? No — keep it
// inside: see below (appended to the kernel through blockIdx check).
// NOTE: finalize is folded into hamming_fused_kernel's block 0 below.

__global__ __launch_bounds__(256) void unused_placeholder() {}

extern "C" void kernel_launch(void* const* d_in, const int* in_sizes, int n_in,
                              void* d_out, int out_size, void* d_ws, size_t ws_size,
                              hipStream_t stream);

// -- Re-define the kernel with finalize included (single definition used) --
__global__ __launch_bounds__(256) void hamming_fused_full_kernel(
        const int* __restrict__ output,
        const int* __restrict__ target,
        const float* __restrict__ codebook,
        unsigned int* __restrict__ partials,
        unsigned int* __restrict__ flags,
        unsigned int* __restrict__ packed,
        float* __restrict__ out) {
    __shared__ uint4 lds[CHUNKS];               // 64000 B
    __shared__ unsigned int wsum[4];

    int base = blockIdx.x * SAMPLES_PER_BLOCK + threadIdx.x;
    int o[4], t[4];
    #pragma unroll
    for (int b = 0; b < 4; b++) {
        o[b] = output[base + b * 256];
        t[b] = target[base + b * 256];
    }

    // ---- Phase 1: distributed pack (blocks 0..249) ----
    if (blockIdx.x < PACKERS) {
        int base_e = blockIdx.x * 2048;
        #pragma unroll
        for (int i = 0; i < 8; i++) {
            int idx = base_e + i * 256 + threadIdx.x;
            float x = codebook[idx];
            unsigned long long m = __ballot(x > 0.5f);
            if ((threadIdx.x & 31) == 0) {
                atomicExch(&packed[idx >> 5],
                           (unsigned int)(m >> (threadIdx.x & 32)));
            }
        }
        __syncthreads();
        if (threadIdx.x == 0) {
            __threadfence();
            atomicExch(&flags[blockIdx.x * WS_LINE_STRIDE], FLAG_MARKER);
        }
    }

    // ---- Phase 2: flag barrier ----
    if (threadIdx.x < PACKERS) {
        while (__hip_atomic_load(&flags[threadIdx.x * WS_LINE_STRIDE],
                                 __ATOMIC_ACQUIRE,
                                 __HIP_MEMORY_SCOPE_AGENT) != FLAG_MARKER) {}
    }
    __syncthreads();

    // ---- Phase 3: stage table -> LDS (swizzled) ----
    const uint4* pk4 = (const uint4*)packed;
    #pragma unroll
    for (int it = 0; it < 16; it++) {
        int g = threadIdx.x + 256 * it;
        if (g < CHUNKS) {
            int r = g >> 2, k = g & 3;
            lds[(r << 2) + ((k + (r >> 2)) & 3)] = pk4[g];
        }
    }
    __syncthreads();

    // ---- Phase 4: gathers + popcount ----
    unsigned int sum = 0;
    #pragma unroll
    for (int b = 0; b < 2; b++) {
        int o0 = o[2 * b], t0 = t[2 * b];
        int o1 = o[2 * b + 1], t1 = t[2 * b + 1];

        uint4 ao[4], at[4], bo[4], bt[4];
        int so0 = (o0 >> 2) & 3, st0 = (t0 >> 2) & 3;
        int so1 = (o1 >> 2) & 3, st1 = (t1 >> 2) & 3;
        #pragma unroll
        for (int k = 0; k < 4; k++) ao[k] = lds[(o0 << 2) + ((k + so0) & 3)];
        #pragma unroll
        for (int k = 0; k < 4; k++) at[k] = lds[(t0 << 2) + ((k + st0) & 3)];
        #pragma unroll
        for (int k = 0; k < 4; k++) bo[k] = lds[(o1 << 2) + ((k + so1) & 3)];
        #pragma unroll
        for (int k = 0; k < 4; k++) bt[k] = lds[(t1 << 2) + ((k + st1) & 3)];

        #pragma unroll
        for (int k = 0; k < 4; k++) {
            sum += __popc(ao[k].x ^ at[k].x) + __popc(ao[k].y ^ at[k].y)
                 + __popc(ao[k].z ^ at[k].z) + __popc(ao[k].w ^ at[k].w);
            sum += __popc(bo[k].x ^ bt[k].x) + __popc(bo[k].y ^ bt[k].y)
                 + __popc(bo[k].z ^ bt[k].z) + __popc(bo[k].w ^ bt[k].w);
        }
    }

    #pragma unroll
    for (int off = 32; off > 0; off >>= 1)
        sum += __shfl_down(sum, off, 64);
    if ((threadIdx.x & 63) == 0)
        wsum[threadIdx.x >> 6] = sum;
    __syncthreads();

    if (threadIdx.x == 0) {
        unsigned int bsum = wsum[0] + wsum[1] + wsum[2] + wsum[3];
        atomicExch(&partials[blockIdx.x * WS_LINE_STRIDE], bsum | PUB_MARKER);
    }

    // ---- Phase 5: block 0 collects all partials and writes the mean ----
    if (blockIdx.x == 0) {
        __syncthreads();    // protect wsum reuse
        unsigned int v;
        do {
            v = __hip_atomic_load(&partials[threadIdx.x * WS_LINE_STRIDE],
                                  __ATOMIC_ACQUIRE, __HIP_MEMORY_SCOPE_AGENT);
        } while (!(v & PUB_MARKER));
        v &= ~PUB_MARKER;

        #pragma unroll
        for (int off = 32; off > 0; off >>= 1)
            v += __shfl_down(v, off, 64);
        if ((threadIdx.x & 63) == 0)
            wsum[threadIdx.x >> 6] = v;
        __syncthreads();
        if (threadIdx.x == 0) {
            unsigned long long total =
                (unsigned long long)wsum[0] + wsum[1] + wsum[2] + wsum[3];
            out[0] = (float)((double)total / (double)B_SIZE);
        }
    }
}

extern "C" void kernel_launch(void* const* d_in, const int* in_sizes, int n_in,
                              void* d_out, int out_size, void* d_ws, size_t ws_size,
                              hipStream_t stream) {
    const int*   output   = (const int*)d_in[0];    // [B] int32
    const int*   target   = (const int*)d_in[1];    // [B] int32
    const float* codebook = (const float*)d_in[2];  // [1000, 512] float32 (0/1)
    float* out = (float*)d_out;

    unsigned int* partials = (unsigned int*)((char*)d_ws + WS_PART_OFF);
    unsigned int* flags    = (unsigned int*)((char*)d_ws + WS_FLAG_OFF);
    unsigned int* packed   = (unsigned int*)((char*)d_ws + WS_PACKED_OFF);

    hamming_fused_full_kernel<<<NBLOCKS, 256, 0, stream>>>(
        output, target, codebook, partials, flags, packed, out);
}

// Round 8
// 63.998 us; speedup vs baseline: 1.3575x; 1.3575x over previous
//
#include <hip/hip_runtime.h>
#include <stdint.h>

#define B_SIZE        262144
#define NUM_CLASSES   1000
#define CODE_LEN      512
#define PACKED_WORDS  (NUM_CLASSES * 16)        // 16000 uint32 = 62.5 KB
#define CHUNKS        (NUM_CLASSES * 4)         // 4000 uint4 chunks
#define HAM_BLOCKS    512                       // 2 blocks/CU (2x64000B LDS fits 160KB)
#define SAMPLES_PER_BLOCK (B_SIZE / HAM_BLOCKS) // 512 -> 2 per thread

// ws layout (bytes):
//   [0]      u32 partials[HAM_BLOCKS], one per 128B line (stride 32 u32)
//   [65536]  packed codebook, 16000 u32
#define WS_PART_OFF     0
#define WS_PART_STRIDE  32      // u32 elements = 128 B
#define WS_PACKED_OFF   65536
#define PUB_MARKER      0x40000000u   // bit30: poison 0xAAAAAAAA has bit30=0

// Kernel 1: pack binary float codebook into bitwords via wave ballot.
// One thread per float element; fully coalesced. Kernel-boundary release
// makes the plain stores visible to kernel 2 on all XCDs.
__global__ __launch_bounds__(256) void pack_kernel(
        const float* __restrict__ codebook,
        uint32_t* __restrict__ packed) {
    int tid = blockIdx.x * blockDim.x + threadIdx.x;
    if (tid < NUM_CLASSES * CODE_LEN) {
        float x = codebook[tid];
        unsigned long long m = __ballot(x > 0.5f);
        if ((tid & 31) == 0) {
            // lane 0 / lane 32 of each wave write their 32-bit halves
            packed[tid >> 5] = (uint32_t)(m >> (threadIdx.x & 32));
        }
    }
}

// Kernel 2: table in LDS (swizzled), 2 samples/thread, block reduce,
// partial published to its OWN 128B line (atomicExch + bit30 marker,
// contention-free). Block 0 finalizes: 256 threads spin on 512 distinct
// lines (2 each) with acquire loads, reduce, write the mean.
__global__ __launch_bounds__(256) void hamming_kernel(
        const int* __restrict__ output,
        const int* __restrict__ target,
        const uint32_t* __restrict__ packed,
        unsigned int* __restrict__ partials,
        float* __restrict__ out) {
    __shared__ uint4 lds[CHUNKS];               // 64000 B -> 2 blocks/CU
    __shared__ unsigned int wsum[4];

    // Prefetch this thread's 4 indices: loads issue now, complete while
    // staging runs.
    int base = blockIdx.x * SAMPLES_PER_BLOCK + threadIdx.x;
    int o0 = output[base],       t0 = target[base];
    int o1 = output[base + 256], t1 = target[base + 256];

    // Stage global packed table -> LDS with bank swizzle:
    // chunk k of row r stored at lds[4r + ((k + (r>>2)) & 3)]
    const uint4* pk4 = (const uint4*)packed;
    #pragma unroll
    for (int it = 0; it < 16; it++) {
        int g = threadIdx.x + 256 * it;
        if (g < CHUNKS) {
            int r = g >> 2, k = g & 3;
            lds[(r << 2) + ((k + (r >> 2)) & 3)] = pk4[g];
        }
    }
    __syncthreads();

    // Issue all 16 LDS gathers before popcounts (ILP).
    uint4 ao[4], at[4], bo[4], bt[4];
    int so0 = (o0 >> 2) & 3, st0 = (t0 >> 2) & 3;
    int so1 = (o1 >> 2) & 3, st1 = (t1 >> 2) & 3;
    #pragma unroll
    for (int k = 0; k < 4; k++) ao[k] = lds[(o0 << 2) + ((k + so0) & 3)];
    #pragma unroll
    for (int k = 0; k < 4; k++) at[k] = lds[(t0 << 2) + ((k + st0) & 3)];
    #pragma unroll
    for (int k = 0; k < 4; k++) bo[k] = lds[(o1 << 2) + ((k + so1) & 3)];
    #pragma unroll
    for (int k = 0; k < 4; k++) bt[k] = lds[(t1 << 2) + ((k + st1) & 3)];

    unsigned int sum = 0;
    #pragma unroll
    for (int k = 0; k < 4; k++) {
        sum += __popc(ao[k].x ^ at[k].x) + __popc(ao[k].y ^ at[k].y)
             + __popc(ao[k].z ^ at[k].z) + __popc(ao[k].w ^ at[k].w);
        sum += __popc(bo[k].x ^ bt[k].x) + __popc(bo[k].y ^ bt[k].y)
             + __popc(bo[k].z ^ bt[k].z) + __popc(bo[k].w ^ bt[k].w);
    }

    // wave(64)-level reduction, then block reduction in LDS
    #pragma unroll
    for (int off = 32; off > 0; off >>= 1)
        sum += __shfl_down(sum, off, 64);
    if ((threadIdx.x & 63) == 0)
        wsum[threadIdx.x >> 6] = sum;
    __syncthreads();

    if (threadIdx.x == 0) {
        unsigned int bsum = wsum[0] + wsum[1] + wsum[2] + wsum[3];
        // own 128B line; marker bit30 flags publication (bsum < 2^20)
        atomicExch(&partials[blockIdx.x * WS_PART_STRIDE], bsum | PUB_MARKER);
    }

    // ---- block 0 collects all 512 partials (2 lines/thread) ----
    if (blockIdx.x == 0) {
        __syncthreads();    // protect wsum reuse below
        unsigned int v0, v1;
        do {
            v0 = __hip_atomic_load(&partials[threadIdx.x * WS_PART_STRIDE],
                                   __ATOMIC_ACQUIRE, __HIP_MEMORY_SCOPE_AGENT);
        } while (!(v0 & PUB_MARKER));
        do {
            v1 = __hip_atomic_load(&partials[(threadIdx.x + 256) * WS_PART_STRIDE],
                                   __ATOMIC_ACQUIRE, __HIP_MEMORY_SCOPE_AGENT);
        } while (!(v1 & PUB_MARKER));
        unsigned int v = (v0 & ~PUB_MARKER) + (v1 & ~PUB_MARKER);

        #pragma unroll
        for (int off = 32; off > 0; off >>= 1)
            v += __shfl_down(v, off, 64);
        if ((threadIdx.x & 63) == 0)
            wsum[threadIdx.x >> 6] = v;
        __syncthreads();
        if (threadIdx.x == 0) {
            unsigned long long total =
                (unsigned long long)wsum[0] + wsum[1] + wsum[2] + wsum[3];
            out[0] = (float)((double)total / (double)B_SIZE);
        }
    }
}

extern "C" void kernel_launch(void* const* d_in, const int* in_sizes, int n_in,
                              void* d_out, int out_size, void* d_ws, size_t ws_size,
                              hipStream_t stream) {
    const int*   output   = (const int*)d_in[0];    // [B] int32
    const int*   target   = (const int*)d_in[1];    // [B] int32
    const float* codebook = (const float*)d_in[2];  // [1000, 512] float32 (0/1)
    float* out = (float*)d_out;

    unsigned int* partials = (unsigned int*)((char*)d_ws + WS_PART_OFF);
    uint32_t*     packed   = (uint32_t*)((char*)d_ws + WS_PACKED_OFF);

    pack_kernel<<<(NUM_CLASSES * CODE_LEN + 255) / 256, 256, 0, stream>>>(
        codebook, packed);
    hamming_kernel<<<HAM_BLOCKS, 256, 0, stream>>>(
        output, target, packed, partials, out);
}